// Round 9
// baseline (168.610 us; speedup 1.0000x reference)
//
#include <hip/hip_runtime.h>
#include <hip/hip_bf16.h>

#define NNODES 20000
#define NEDGES 320000
#define BATCH  2
#define D      128
#define EPSF   1e-5f
#define QTM    128    // rows per qkv block
#define XS_LD  136    // ushorts per Hs row: 128 + 8 pad
#define MAXDEG 64
#define NROWS  (BATCH * NNODES)

typedef __attribute__((ext_vector_type(8))) short bf16x8;
typedef __attribute__((ext_vector_type(4))) float f32x4;

static __device__ __forceinline__ unsigned short f2bf(float f) {
    __hip_bfloat16 h = __float2bfloat16(f);
    return *reinterpret_cast<unsigned short*>(&h);
}
static __device__ __forceinline__ float bfu(unsigned short u) {
    union { unsigned int i; float f; } cv;
    cv.i = ((unsigned int)u) << 16;
    return cv.f;
}

// ---------------- prep: frag-ordered bf16 weights (blocks 0..31) + cursor clear (32..110) ----
__global__ __launch_bounds__(256) void prep_kernel(
    const float* __restrict__ Wp, const float* __restrict__ Wq,
    const float* __restrict__ Wk, const float* __restrict__ Wv,
    unsigned short* __restrict__ WF,
    int* __restrict__ cursor)
{
    int bid = blockIdx.x;
    if (bid < 32) {
        int sg = bid * 256 + threadIdx.x;   // slot 0..8191
        int mat = sg >> 11, rem = sg & 2047;
        int f = rem >> 6, l = rem & 63;
        int nt = f >> 2, ks = f & 3;
        int c = l & 15, g = l >> 4;
        const float* W = (mat == 0) ? Wp : (mat == 1) ? Wq : (mat == 2) ? Wk : Wv;
        int n = nt * 16 + c;
        #pragma unroll
        for (int i = 0; i < 8; ++i) {
            int k = ks * 32 + g * 8 + i;
            WF[(size_t)sg * 8 + i] = f2bf(W[k * 128 + n]);
        }
    } else {
        int idx = (bid - 32) * 256 + threadIdx.x;
        if (idx < NNODES) cursor[idx] = 0;
    }
}

// ---------------- padded-CSR scatter (srcs only) ----------------
__global__ __launch_bounds__(256) void scatter_pad_kernel(
    const int* __restrict__ src, const int* __restrict__ dst,
    int* __restrict__ cursor,             // exits holding deg
    int* __restrict__ srcs_pad)           // [NNODES][MAXDEG]
{
    int e = blockIdx.x * 256 + threadIdx.x;
    if (e >= NEDGES) return;
    int d = dst[e], s = src[e];
    int slot = atomicAdd(&cursor[d], 1);
    if (slot < MAXDEG) srcs_pad[d * MAXDEG + slot] = s;
}

// ---------------- fused QKV via bf16 MFMA: 128 rows/block, 2 row-frags/wave (B-reuse 2x) ----
// h = x@Wp ; Q = h@Wq+bq ; K folded into alpha per col-slice ; V = h@Wv+bv
// hhv layout: [row][0..127]=h, [row][128..255]=V (bf16)

__global__ __launch_bounds__(256) void qkv_mfma_kernel(
    const float* __restrict__ x,
    const unsigned short* __restrict__ WF,
    const float* __restrict__ Bq, const float* __restrict__ Bk, const float* __restrict__ Bv,
    unsigned short* __restrict__ hhv,
    float* __restrict__ a_out)
{
    __shared__ unsigned short Wbuf[16384];       // 32 KB
    __shared__ unsigned short Hs[QTM][XS_LD];    // 34.8 KB
    const int t = threadIdx.x;
    const long row0 = (long)blockIdx.x * QTM;
    const int w = t >> 6, l = t & 63;
    const int g = l >> 4, c = l & 15;
    const int rw = w * 32;                       // wave's 32-row base

    bf16x8 wreg[8];
    #define LOAD_W_REGS(MAT_OFF)                                        \
        _Pragma("unroll")                                               \
        for (int q = 0; q < 8; ++q)                                     \
            wreg[q] = *(const bf16x8*)(WF + (MAT_OFF) + (q * 256 + t) * 8);
    #define WRITE_W_LDS()                                               \
        _Pragma("unroll")                                               \
        for (int q = 0; q < 8; ++q)                                     \
            *(bf16x8*)&Wbuf[(q * 256 + t) * 8] = wreg[q];

    LOAD_W_REGS(0)                               // Wp -> regs

    // ---- x A-fragments (2 row-frags) from global, clamped ----
    bf16x8 ax[2][4];
    #pragma unroll
    for (int rf = 0; rf < 2; ++rf) {
        long r = row0 + rw + rf * 16 + c;
        if (r >= NROWS) r = NROWS - 1;
        const float* xr = x + r * D;
        #pragma unroll
        for (int ks = 0; ks < 4; ++ks) {
            float4 u0 = *(const float4*)(xr + ks * 32 + g * 8);
            float4 u1 = *(const float4*)(xr + ks * 32 + g * 8 + 4);
            bf16x8 f;
            f[0] = (short)f2bf(u0.x); f[1] = (short)f2bf(u0.y);
            f[2] = (short)f2bf(u0.z); f[3] = (short)f2bf(u0.w);
            f[4] = (short)f2bf(u1.x); f[5] = (short)f2bf(u1.y);
            f[6] = (short)f2bf(u1.z); f[7] = (short)f2bf(u1.w);
            ax[rf][ks] = f;
        }
    }

    WRITE_W_LDS();                               // Wp -> LDS
    __syncthreads();                             // (1)
    LOAD_W_REGS(16384)                           // prefetch Wq during m1

    // ---- m1: h = x @ Wp ----
    f32x4 hacc[2][8];
    #pragma unroll
    for (int rf = 0; rf < 2; ++rf)
        #pragma unroll
        for (int nt = 0; nt < 8; ++nt) hacc[rf][nt] = f32x4{0.f, 0.f, 0.f, 0.f};
    #pragma unroll
    for (int nt = 0; nt < 8; ++nt)
        #pragma unroll
        for (int ks = 0; ks < 4; ++ks) {
            bf16x8 b = *(const bf16x8*)&Wbuf[((nt * 4 + ks) * 64 + l) * 8];
            #pragma unroll
            for (int rf = 0; rf < 2; ++rf)
                hacc[rf][nt] = __builtin_amdgcn_mfma_f32_16x16x32_bf16(ax[rf][ks], b, hacc[rf][nt], 0, 0, 0);
        }
    #pragma unroll
    for (int rf = 0; rf < 2; ++rf)
        #pragma unroll
        for (int nt = 0; nt < 8; ++nt)
            #pragma unroll
            for (int i = 0; i < 4; ++i)
                Hs[rw + rf * 16 + 4 * g + i][nt * 16 + c] = f2bf(hacc[rf][nt][i]);
    __syncthreads();                             // (2) all m1 Wbuf reads + Hs writes done

    // ---- h rows -> global, A-frags of h ----
    #pragma unroll
    for (int q = 0; q < 8; ++q) {
        int ch = q * 256 + t;                    // 2048 chunks of 8 ushorts
        int r = ch >> 4, off = (ch & 15) << 3;
        if (row0 + r < NROWS)
            *(bf16x8*)(hhv + (row0 + r) * 256 + off) = *(const bf16x8*)&Hs[r][off];
    }
    bf16x8 ah[2][4];
    #pragma unroll
    for (int rf = 0; rf < 2; ++rf)
        #pragma unroll
        for (int ks = 0; ks < 4; ++ks)
            ah[rf][ks] = *(const bf16x8*)&Hs[rw + rf * 16 + c][ks * 32 + g * 8];

    WRITE_W_LDS();                               // Wq -> LDS
    __syncthreads();                             // (3)
    LOAD_W_REGS(32768)                           // prefetch Wk during mQ

    // ---- mQ ----
    f32x4 qacc[2][8];
    #pragma unroll
    for (int rf = 0; rf < 2; ++rf)
        #pragma unroll
        for (int nt = 0; nt < 8; ++nt) qacc[rf][nt] = f32x4{0.f, 0.f, 0.f, 0.f};
    #pragma unroll
    for (int nt = 0; nt < 8; ++nt)
        #pragma unroll
        for (int ks = 0; ks < 4; ++ks) {
            bf16x8 b = *(const bf16x8*)&Wbuf[((nt * 4 + ks) * 64 + l) * 8];
            #pragma unroll
            for (int rf = 0; rf < 2; ++rf)
                qacc[rf][nt] = __builtin_amdgcn_mfma_f32_16x16x32_bf16(ah[rf][ks], b, qacc[rf][nt], 0, 0, 0);
        }
    __syncthreads();                             // (4) done reading Wq

    WRITE_W_LDS();                               // Wk -> LDS
    __syncthreads();                             // (5)
    LOAD_W_REGS(49152)                           // prefetch Wv during mK

    // ---- mK folded into alpha per col-slice ----
    float p[2][4] = {{0.f,0.f,0.f,0.f},{0.f,0.f,0.f,0.f}};
    #pragma unroll
    for (int nt = 0; nt < 8; ++nt) {
        f32x4 kacc[2] = {f32x4{0.f,0.f,0.f,0.f}, f32x4{0.f,0.f,0.f,0.f}};
        #pragma unroll
        for (int ks = 0; ks < 4; ++ks) {
            bf16x8 b = *(const bf16x8*)&Wbuf[((nt * 4 + ks) * 64 + l) * 8];
            #pragma unroll
            for (int rf = 0; rf < 2; ++rf)
                kacc[rf] = __builtin_amdgcn_mfma_f32_16x16x32_bf16(ah[rf][ks], b, kacc[rf], 0, 0, 0);
        }
        float bq = Bq[nt * 16 + c];
        float bk = Bk[nt * 16 + c];
        #pragma unroll
        for (int rf = 0; rf < 2; ++rf)
            #pragma unroll
            for (int i = 0; i < 4; ++i)
                p[rf][i] += (qacc[rf][nt][i] + bq) * (kacc[rf][i] + bk);
    }
    #pragma unroll
    for (int off = 1; off < 16; off <<= 1)
        #pragma unroll
        for (int rf = 0; rf < 2; ++rf)
            #pragma unroll
            for (int i = 0; i < 4; ++i)
                p[rf][i] += __shfl_xor(p[rf][i], off, 64);
    if (c == 0) {
        #pragma unroll
        for (int rf = 0; rf < 2; ++rf)
            #pragma unroll
            for (int i = 0; i < 4; ++i) {
                long r = row0 + rw + rf * 16 + 4 * g + i;
                if (r < NROWS) a_out[r] = p[rf][i] * 0.25f;
            }
    }
    __syncthreads();                             // (6) done reading Wk

    WRITE_W_LDS();                               // Wv -> LDS
    __syncthreads();                             // (7)

    // ---- mV per col-slice, straight into Hs ----
    #pragma unroll
    for (int nt = 0; nt < 8; ++nt) {
        f32x4 vacc[2] = {f32x4{0.f,0.f,0.f,0.f}, f32x4{0.f,0.f,0.f,0.f}};
        #pragma unroll
        for (int ks = 0; ks < 4; ++ks) {
            bf16x8 b = *(const bf16x8*)&Wbuf[((nt * 4 + ks) * 64 + l) * 8];
            #pragma unroll
            for (int rf = 0; rf < 2; ++rf)
                vacc[rf] = __builtin_amdgcn_mfma_f32_16x16x32_bf16(ah[rf][ks], b, vacc[rf], 0, 0, 0);
        }
        float bv = Bv[nt * 16 + c];
        #pragma unroll
        for (int rf = 0; rf < 2; ++rf)
            #pragma unroll
            for (int i = 0; i < 4; ++i)
                Hs[rw + rf * 16 + 4 * g + i][nt * 16 + c] = f2bf(vacc[rf][i] + bv);
    }
    __syncthreads();                             // (8)
    #pragma unroll
    for (int q = 0; q < 8; ++q) {
        int ch = q * 256 + t;
        int r = ch >> 4, off = (ch & 15) << 3;
        if (row0 + r < NROWS)
            *(bf16x8*)(hhv + (row0 + r) * 256 + 128 + off) = *(const bf16x8*)&Hs[r][off];
    }
    #undef LOAD_W_REGS
    #undef WRITE_W_LDS
}

// ---------------- aggregation: one WAVE per node; 32 lanes x 16B per edge row ----------------
// 256 thr = 4 waves = 4 nodes/block. Lane role: eh = edge-of-pair, half = h/hv, cq = 16B chunk.

__global__ __launch_bounds__(256) void agg_kernel(
    const unsigned short* __restrict__ hhv,
    const float* __restrict__ a,          // [BATCH][NNODES]
    const int* __restrict__ deg_arr,
    const int* __restrict__ srcs_pad,     // [NNODES][MAXDEG]
    const float* __restrict__ ln_g, const float* __restrict__ ln_b,
    float* __restrict__ out)
{
    const int t = threadIdx.x;
    const int w = t >> 6, l = t & 63;
    const int flat = blockIdx.x * 4 + w;
    const int n = flat % NNODES;
    const int b = flat / NNODES;
    const int bN = b * NNODES;
    const int deg = min(deg_arr[n], MAXDEG);
    const bool valid = l < deg;

    // coalesced srcs load, L2-resident alpha gather
    int   sr_l = valid ? srcs_pad[n * MAXDEG + l] : 0;
    float av_l = valid ? a[bN + sr_l] : -1e30f;

    // softmax stats in-register
    float m = av_l;
    #pragma unroll
    for (int off = 32; off >= 1; off >>= 1) m = fmaxf(m, __shfl_xor(m, off, 64));
    float e_l = valid ? __expf(av_l - m) : 0.f;
    float s = e_l;
    #pragma unroll
    for (int off = 32; off >= 1; off >>= 1) s += __shfl_xor(s, off, 64);
    const float inv_s = (deg > 0) ? 1.f / s : 0.f;
    const float inv_d = 1.f / (float)max(deg, 1);
    const float w_l = e_l * inv_s;

    const int eh   = l >> 5;        // which edge of the pair
    const int half = (l >> 4) & 1;  // 0: h bytes (skip), 1: hv bytes (weighted V)
    const int cq   = l & 15;        // 16-B chunk = channels 8*cq..+7
    float acc[8] = {0,0,0,0,0,0,0,0};
    const long rowBase = (long)bN * 256 + half * 128 + (cq << 3);

    const int iters = (deg + 1) >> 1;
    for (int jj = 0; jj < iters; ++jj) {
        int sel = (jj << 1) + eh;
        bool ev = sel < deg;
        int selc = ev ? sel : 0;
        int srj  = __shfl(sr_l, selc, 64);
        float wj = __shfl(w_l,  selc, 64);
        float mul = half ? (ev ? wj : 0.f) : (ev ? 1.f : 0.f);
        bf16x8 d = *(const bf16x8*)(hhv + rowBase + (long)srj * 256);
        #pragma unroll
        for (int i = 0; i < 8; ++i)
            acc[i] += mul * bfu((unsigned short)d[i]);
    }

    // exchange halves: lane l <-> l^16 (other of h/hv, same cq, same eh)
    float accv[8], sk[8];
    #pragma unroll
    for (int i = 0; i < 8; ++i) {
        float other = __shfl_xor(acc[i], 16, 64);
        accv[i] = half ? acc[i] : other;
        sk[i]   = half ? other  : acc[i];
    }
    // fold the two edge-groups: l <-> l^32
    #pragma unroll
    for (int i = 0; i < 8; ++i) {
        accv[i] += __shfl_xor(accv[i], 32, 64);
        sk[i]   += __shfl_xor(sk[i],   32, 64);
    }
    float v[8];
    float sum = 0.f, sq = 0.f;
    #pragma unroll
    for (int i = 0; i < 8; ++i) {
        v[i] = accv[i] + sk[i] * inv_d;
        sum += v[i];
        sq  += v[i] * v[i];
    }
    // LN reduce across the 16 cq lanes (xor 1,2,4,8 stays within the group)
    #pragma unroll
    for (int off = 8; off >= 1; off >>= 1) {
        sum += __shfl_xor(sum, off, 64);
        sq  += __shfl_xor(sq,  off, 64);
    }
    float mu   = sum * (1.f / 128.f);
    float var  = sq * (1.f / 128.f) - mu * mu;
    float rstd = rsqrtf(var + EPSF);
    if (l < 16) {                   // eh==0 && half==0 lanes write the row
        float4 g0 = *(const float4*)(ln_g + (cq << 3));
        float4 g1 = *(const float4*)(ln_g + (cq << 3) + 4);
        float4 b0 = *(const float4*)(ln_b + (cq << 3));
        float4 b1 = *(const float4*)(ln_b + (cq << 3) + 4);
        float4 o0, o1;
        o0.x = (v[0] - mu) * rstd * g0.x + b0.x;
        o0.y = (v[1] - mu) * rstd * g0.y + b0.y;
        o0.z = (v[2] - mu) * rstd * g0.z + b0.z;
        o0.w = (v[3] - mu) * rstd * g0.w + b0.w;
        o1.x = (v[4] - mu) * rstd * g1.x + b1.x;
        o1.y = (v[5] - mu) * rstd * g1.y + b1.y;
        o1.z = (v[6] - mu) * rstd * g1.z + b1.z;
        o1.w = (v[7] - mu) * rstd * g1.w + b1.w;
        float* op = out + (long)flat * D + (cq << 3);
        *(float4*)op = o0;
        *(float4*)(op + 4) = o1;
    }
}

// ---------------- launch ----------------

extern "C" void kernel_launch(void* const* d_in, const int* in_sizes, int n_in,
                              void* d_out, int out_size, void* d_ws, size_t ws_size,
                              hipStream_t stream)
{
    const float* x    = (const float*)d_in[0];
    const float* Wp   = (const float*)d_in[1];
    const float* Wq   = (const float*)d_in[2];
    const float* Bq   = (const float*)d_in[3];
    const float* Wk   = (const float*)d_in[4];
    const float* Bk   = (const float*)d_in[5];
    const float* Wv   = (const float*)d_in[6];
    const float* Bv   = (const float*)d_in[7];
    const float* ln_g = (const float*)d_in[8];
    const float* ln_b = (const float*)d_in[9];
    const int*   ei   = (const int*)d_in[10];
    const int* esrc = ei;
    const int* edst = ei + NEDGES;
    float* out = (float*)d_out;

    char* p = (char*)d_ws;
    auto alloc = [&](size_t bytes) -> char* {
        char* r = p;
        p += (bytes + 255) & ~(size_t)255;
        return r;
    };
    unsigned short* hhv = (unsigned short*)alloc((size_t)NROWS * 256 * 2);
    float* a        = (float*)alloc((size_t)NROWS * 4);
    int* cursor     = (int*)alloc((size_t)NNODES * 4);
    int* srcs_pad   = (int*)alloc((size_t)NNODES * MAXDEG * 4);
    unsigned short* WF = (unsigned short*)alloc((size_t)4 * 128 * 128 * 2);

    prep_kernel<<<111, 256, 0, stream>>>(Wp, Wq, Wk, Wv, WF, cursor);
    scatter_pad_kernel<<<(NEDGES + 255) / 256, 256, 0, stream>>>(esrc, edst, cursor, srcs_pad);
    qkv_mfma_kernel<<<(NROWS + QTM - 1) / QTM, 256, 0, stream>>>(
        x, WF, Bq, Bk, Bv, hhv, a);
    agg_kernel<<<NROWS / 4, 256, 0, stream>>>(
        hhv, a, cursor, srcs_pad, ln_g, ln_b, out);
}

// Round 10
// 164.264 us; speedup vs baseline: 1.0265x; 1.0265x over previous
//
#include <hip/hip_runtime.h>
#include <hip/hip_bf16.h>

#define NNODES 20000
#define NEDGES 320000
#define BATCH  2
#define D      128
#define EPSF   1e-5f
#define QTM    64     // rows per block (4 waves x 16 rows)
#define XS_LD  136
#define MAXDEG 64
#define NROWS  (BATCH * NNODES)

typedef __attribute__((ext_vector_type(8))) short bf16x8;
typedef __attribute__((ext_vector_type(4))) float f32x4;

static __device__ __forceinline__ unsigned short f2bf(float f) {
    __hip_bfloat16 h = __float2bfloat16(f);
    return *reinterpret_cast<unsigned short*>(&h);
}
static __device__ __forceinline__ float bfu(unsigned short u) {
    union { unsigned int i; float f; } cv;
    cv.i = ((unsigned int)u) << 16;
    return cv.f;
}

// ---------------- prep: frag-ordered bf16 weights (blocks 0..31) + cursor clear (32..110) ----
__global__ __launch_bounds__(256) void prep_kernel(
    const float* __restrict__ Wp, const float* __restrict__ Wq,
    const float* __restrict__ Wk, const float* __restrict__ Wv,
    unsigned short* __restrict__ WF,
    int* __restrict__ cursor)
{
    int bid = blockIdx.x;
    if (bid < 32) {
        int sg = bid * 256 + threadIdx.x;   // slot 0..8191
        int mat = sg >> 11, rem = sg & 2047;
        int f = rem >> 6, l = rem & 63;
        int nt = f >> 2, ks = f & 3;
        int c = l & 15, g = l >> 4;
        const float* W = (mat == 0) ? Wp : (mat == 1) ? Wq : (mat == 2) ? Wk : Wv;
        int n = nt * 16 + c;
        #pragma unroll
        for (int i = 0; i < 8; ++i) {
            int k = ks * 32 + g * 8 + i;
            WF[(size_t)sg * 8 + i] = f2bf(W[k * 128 + n]);
        }
    } else {
        int idx = (bid - 32) * 256 + threadIdx.x;
        if (idx < NNODES) cursor[idx] = 0;
    }
}

// ---------------- padded-CSR scatter (srcs only) ----------------
__global__ __launch_bounds__(256) void scatter_pad_kernel(
    const int* __restrict__ src, const int* __restrict__ dst,
    int* __restrict__ cursor,             // exits holding deg
    int* __restrict__ srcs_pad)           // [NNODES][MAXDEG]
{
    int e = blockIdx.x * 256 + threadIdx.x;
    if (e >= NEDGES) return;
    int d = dst[e], s = src[e];
    int slot = atomicAdd(&cursor[d], 1);
    if (slot < MAXDEG) srcs_pad[d * MAXDEG + slot] = s;
}

#define DECL_STAGE_MACROS                                               \
    bf16x8 wreg[8];
#define LOAD_W_REGS(MAT_OFF)                                            \
    _Pragma("unroll")                                                   \
    for (int q = 0; q < 8; ++q)                                         \
        wreg[q] = *(const bf16x8*)(WF + (MAT_OFF) + (q * 256 + t) * 8);
#define WRITE_W_LDS()                                                   \
    _Pragma("unroll")                                                   \
    for (int q = 0; q < 8; ++q)                                         \
        *(bf16x8*)&Wbuf[(q * 256 + t) * 8] = wreg[q];

// ---------------- kernel A: h = x@Wp -> hhv[.][0:128]; V = h@Wv+bv -> hhv[.][128:256] ----
// 4 waves x independent 16-row tiles; h round-trips a WAVE-PRIVATE LDS slice (no barrier);
// only 3 block barriers (around the two weight stages).

__global__ __launch_bounds__(256) void hv_kernel(
    const float* __restrict__ x,
    const unsigned short* __restrict__ WF,
    const float* __restrict__ Bv,
    unsigned short* __restrict__ hhv)
{
    __shared__ unsigned short Wbuf[16384];          // 32 KB
    __shared__ unsigned short Hs[4][16][XS_LD];     // 17.4 KB wave-private slices
    const int t = threadIdx.x;
    const long row0 = (long)blockIdx.x * QTM;
    const int w = t >> 6, l = t & 63;
    const int g = l >> 4, c = l & 15;
    const int rw = w * 16;
    DECL_STAGE_MACROS

    LOAD_W_REGS(0)                                  // Wp -> regs

    // x A-fragments from global (fp32 -> bf16); grid exact (40000/64=625)
    bf16x8 ax[4];
    {
        const float* xr = x + (row0 + rw + c) * D;
        #pragma unroll
        for (int ks = 0; ks < 4; ++ks) {
            float4 u0 = *(const float4*)(xr + ks * 32 + g * 8);
            float4 u1 = *(const float4*)(xr + ks * 32 + g * 8 + 4);
            bf16x8 f;
            f[0] = (short)f2bf(u0.x); f[1] = (short)f2bf(u0.y);
            f[2] = (short)f2bf(u0.z); f[3] = (short)f2bf(u0.w);
            f[4] = (short)f2bf(u1.x); f[5] = (short)f2bf(u1.y);
            f[6] = (short)f2bf(u1.z); f[7] = (short)f2bf(u1.w);
            ax[ks] = f;
        }
    }

    WRITE_W_LDS();                                  // Wp -> LDS
    __syncthreads();                                // (1)
    LOAD_W_REGS(49152)                              // prefetch Wv during m1

    // m1: h = x @ Wp
    f32x4 hacc[8];
    #pragma unroll
    for (int nt = 0; nt < 8; ++nt) hacc[nt] = f32x4{0.f, 0.f, 0.f, 0.f};
    #pragma unroll
    for (int nt = 0; nt < 8; ++nt)
        #pragma unroll
        for (int ks = 0; ks < 4; ++ks) {
            bf16x8 b = *(const bf16x8*)&Wbuf[((nt * 4 + ks) * 64 + l) * 8];
            hacc[nt] = __builtin_amdgcn_mfma_f32_16x16x32_bf16(ax[ks], b, hacc[nt], 0, 0, 0);
        }
    // h -> wave-private slice (no barrier; same-wave LDS ordering via lgkmcnt)
    #pragma unroll
    for (int nt = 0; nt < 8; ++nt)
        #pragma unroll
        for (int i = 0; i < 4; ++i)
            Hs[w][4 * g + i][nt * 16 + c] = f2bf(hacc[nt][i]);

    // h rows -> global (wave-local chunks), A-frags of h from slice
    #pragma unroll
    for (int q = 0; q < 4; ++q) {
        int ch = q * 64 + l;                        // 256 chunks of 8 ushorts (16 rows x 16)
        int r = ch >> 4, off = (ch & 15) << 3;
        *(bf16x8*)(hhv + (row0 + rw + r) * 256 + off) = *(const bf16x8*)&Hs[w][r][off];
    }
    bf16x8 ah[4];
    #pragma unroll
    for (int ks = 0; ks < 4; ++ks)
        ah[ks] = *(const bf16x8*)&Hs[w][c][ks * 32 + g * 8];

    __syncthreads();                                // (2) all waves done reading Wp
    WRITE_W_LDS();                                  // Wv -> LDS
    __syncthreads();                                // (3)

    // mV: V = h @ Wv + bv
    #pragma unroll
    for (int nt = 0; nt < 8; ++nt) {
        f32x4 vacc = f32x4{0.f, 0.f, 0.f, 0.f};
        #pragma unroll
        for (int ks = 0; ks < 4; ++ks) {
            bf16x8 b = *(const bf16x8*)&Wbuf[((nt * 4 + ks) * 64 + l) * 8];
            vacc = __builtin_amdgcn_mfma_f32_16x16x32_bf16(ah[ks], b, vacc, 0, 0, 0);
        }
        float bv = Bv[nt * 16 + c];
        #pragma unroll
        for (int i = 0; i < 4; ++i)
            Hs[w][4 * g + i][nt * 16 + c] = f2bf(vacc[i] + bv);
    }
    #pragma unroll
    for (int q = 0; q < 4; ++q) {
        int ch = q * 64 + l;
        int r = ch >> 4, off = (ch & 15) << 3;
        *(bf16x8*)(hhv + (row0 + rw + r) * 256 + 128 + off) = *(const bf16x8*)&Hs[w][r][off];
    }
}

// ---------------- kernel B: alpha = dot(h@Wq+bq, h@Wk+bk)*0.25 ----------------
__global__ __launch_bounds__(256) void alpha_kernel(
    const unsigned short* __restrict__ hhv,
    const unsigned short* __restrict__ WF,
    const float* __restrict__ Bq, const float* __restrict__ Bk,
    float* __restrict__ a_out)
{
    __shared__ unsigned short Wbuf[16384];
    const int t = threadIdx.x;
    const long row0 = (long)blockIdx.x * QTM;
    const int w = t >> 6, l = t & 63;
    const int g = l >> 4, c = l & 15;
    const int rw = w * 16;
    DECL_STAGE_MACROS

    LOAD_W_REGS(16384)                              // Wq -> regs

    // h A-fragments from hhv (h half of each 256-ushort row)
    bf16x8 ah[4];
    {
        const unsigned short* hr = hhv + (row0 + rw + c) * 256;
        #pragma unroll
        for (int ks = 0; ks < 4; ++ks)
            ah[ks] = *(const bf16x8*)(hr + ks * 32 + g * 8);
    }

    WRITE_W_LDS();                                  // Wq -> LDS
    __syncthreads();                                // (1)
    LOAD_W_REGS(32768)                              // prefetch Wk during mQ

    f32x4 qacc[8];
    #pragma unroll
    for (int nt = 0; nt < 8; ++nt) qacc[nt] = f32x4{0.f, 0.f, 0.f, 0.f};
    #pragma unroll
    for (int nt = 0; nt < 8; ++nt)
        #pragma unroll
        for (int ks = 0; ks < 4; ++ks) {
            bf16x8 b = *(const bf16x8*)&Wbuf[((nt * 4 + ks) * 64 + l) * 8];
            qacc[nt] = __builtin_amdgcn_mfma_f32_16x16x32_bf16(ah[ks], b, qacc[nt], 0, 0, 0);
        }
    __syncthreads();                                // (2)
    WRITE_W_LDS();                                  // Wk -> LDS
    __syncthreads();                                // (3)

    // mK folded into alpha per col-slice
    float p[4] = {0.f, 0.f, 0.f, 0.f};
    #pragma unroll
    for (int nt = 0; nt < 8; ++nt) {
        f32x4 kacc = f32x4{0.f, 0.f, 0.f, 0.f};
        #pragma unroll
        for (int ks = 0; ks < 4; ++ks) {
            bf16x8 b = *(const bf16x8*)&Wbuf[((nt * 4 + ks) * 64 + l) * 8];
            kacc = __builtin_amdgcn_mfma_f32_16x16x32_bf16(ah[ks], b, kacc, 0, 0, 0);
        }
        float bq = Bq[nt * 16 + c];
        float bk = Bk[nt * 16 + c];
        #pragma unroll
        for (int i = 0; i < 4; ++i)
            p[i] += (qacc[nt][i] + bq) * (kacc[i] + bk);
    }
    #pragma unroll
    for (int off = 1; off < 16; off <<= 1)
        #pragma unroll
        for (int i = 0; i < 4; ++i) p[i] += __shfl_xor(p[i], off, 64);
    if (c == 0)
        #pragma unroll
        for (int i = 0; i < 4; ++i)
            a_out[row0 + rw + 4 * g + i] = p[i] * 0.25f;
}

// ---------------- aggregation: one WAVE per node; 16B/lane; 4 rows in flight ----------------
__global__ __launch_bounds__(256) void agg_kernel(
    const unsigned short* __restrict__ hhv,
    const float* __restrict__ a,
    const int* __restrict__ deg_arr,
    const int* __restrict__ srcs_pad,
    const float* __restrict__ ln_g, const float* __restrict__ ln_b,
    float* __restrict__ out)
{
    const int t = threadIdx.x;
    const int w = t >> 6, l = t & 63;
    const int flat = blockIdx.x * 4 + w;
    const int n = flat % NNODES;
    const int b = flat / NNODES;
    const int bN = b * NNODES;
    const int deg = min(deg_arr[n], MAXDEG);
    const bool valid = l < deg;

    int   sr_l = valid ? srcs_pad[n * MAXDEG + l] : 0;
    float av_l = valid ? a[bN + sr_l] : -1e30f;

    float m = av_l;
    #pragma unroll
    for (int off = 32; off >= 1; off >>= 1) m = fmaxf(m, __shfl_xor(m, off, 64));
    float e_l = valid ? __expf(av_l - m) : 0.f;
    float s = e_l;
    #pragma unroll
    for (int off = 32; off >= 1; off >>= 1) s += __shfl_xor(s, off, 64);
    const float inv_s = (deg > 0) ? 1.f / s : 0.f;
    const float inv_d = 1.f / (float)max(deg, 1);
    const float w_l = e_l * inv_s;

    const int eh   = l >> 5;        // which edge of the pair
    const int half = (l >> 4) & 1;  // 0: h (skip), 1: hv (weighted V)
    const int cq   = l & 15;        // 16-B chunk = channels 8*cq..+7
    float acc[8] = {0,0,0,0,0,0,0,0};
    const long rowBase = (long)bN * 256 + half * 128 + (cq << 3);

    // PREP(jj): pair jj, this lane's edge = 2*jj+eh; out-of-range -> mul 0, row 0 (safe)
    #define PREP(JJ, OF, MU)  {                                         \
        int sel = ((JJ) << 1) + eh;                                     \
        bool ev = sel < deg;                                            \
        int sc = ev ? sel : 0;                                          \
        int srj = __shfl(sr_l, sc, 64);                                 \
        float wj = __shfl(w_l, sc, 64);                                 \
        MU = half ? (ev ? wj : 0.f) : (ev ? 1.f : 0.f);                 \
        OF = rowBase + (long)srj * 256;  }

    const int iters = (deg + 1) >> 1;
    for (int j0 = 0; j0 < iters; j0 += 4) {
        long oa, ob, oc, od; float ma, mb, mc, md;
        PREP(j0,     oa, ma)
        PREP(j0 + 1, ob, mb)
        PREP(j0 + 2, oc, mc)
        PREP(j0 + 3, od, md)
        bf16x8 da = *(const bf16x8*)(hhv + oa);     // 4 loads in flight
        bf16x8 db = *(const bf16x8*)(hhv + ob);
        bf16x8 dc = *(const bf16x8*)(hhv + oc);
        bf16x8 dd = *(const bf16x8*)(hhv + od);
        #pragma unroll
        for (int i = 0; i < 8; ++i) acc[i] += ma * bfu((unsigned short)da[i]);
        #pragma unroll
        for (int i = 0; i < 8; ++i) acc[i] += mb * bfu((unsigned short)db[i]);
        #pragma unroll
        for (int i = 0; i < 8; ++i) acc[i] += mc * bfu((unsigned short)dc[i]);
        #pragma unroll
        for (int i = 0; i < 8; ++i) acc[i] += md * bfu((unsigned short)dd[i]);
    }
    #undef PREP

    // exchange halves: lane l <-> l^16
    float accv[8], sk[8];
    #pragma unroll
    for (int i = 0; i < 8; ++i) {
        float other = __shfl_xor(acc[i], 16, 64);
        accv[i] = half ? acc[i] : other;
        sk[i]   = half ? other  : acc[i];
    }
    #pragma unroll
    for (int i = 0; i < 8; ++i) {
        accv[i] += __shfl_xor(accv[i], 32, 64);
        sk[i]   += __shfl_xor(sk[i],   32, 64);
    }
    float v[8];
    float sum = 0.f, sq = 0.f;
    #pragma unroll
    for (int i = 0; i < 8; ++i) {
        v[i] = accv[i] + sk[i] * inv_d;
        sum += v[i];
        sq  += v[i] * v[i];
    }
    #pragma unroll
    for (int off = 8; off >= 1; off >>= 1) {
        sum += __shfl_xor(sum, off, 64);
        sq  += __shfl_xor(sq,  off, 64);
    }
    float mu   = sum * (1.f / 128.f);
    float var  = sq * (1.f / 128.f) - mu * mu;
    float rstd = rsqrtf(var + EPSF);
    if (l < 16) {
        float4 g0 = *(const float4*)(ln_g + (cq << 3));
        float4 g1 = *(const float4*)(ln_g + (cq << 3) + 4);
        float4 b0 = *(const float4*)(ln_b + (cq << 3));
        float4 b1 = *(const float4*)(ln_b + (cq << 3) + 4);
        float4 o0, o1;
        o0.x = (v[0] - mu) * rstd * g0.x + b0.x;
        o0.y = (v[1] - mu) * rstd * g0.y + b0.y;
        o0.z = (v[2] - mu) * rstd * g0.z + b0.z;
        o0.w = (v[3] - mu) * rstd * g0.w + b0.w;
        o1.x = (v[4] - mu) * rstd * g1.x + b1.x;
        o1.y = (v[5] - mu) * rstd * g1.y + b1.y;
        o1.z = (v[6] - mu) * rstd * g1.z + b1.z;
        o1.w = (v[7] - mu) * rstd * g1.w + b1.w;
        float* op = out + (long)flat * D + (cq << 3);
        *(float4*)op = o0;
        *(float4*)(op + 4) = o1;
    }
}

// ---------------- launch ----------------

extern "C" void kernel_launch(void* const* d_in, const int* in_sizes, int n_in,
                              void* d_out, int out_size, void* d_ws, size_t ws_size,
                              hipStream_t stream)
{
    const float* x    = (const float*)d_in[0];
    const float* Wp   = (const float*)d_in[1];
    const float* Wq   = (const float*)d_in[2];
    const float* Bq   = (const float*)d_in[3];
    const float* Wk   = (const float*)d_in[4];
    const float* Bk   = (const float*)d_in[5];
    const float* Wv   = (const float*)d_in[6];
    const float* Bv   = (const float*)d_in[7];
    const float* ln_g = (const float*)d_in[8];
    const float* ln_b = (const float*)d_in[9];
    const int*   ei   = (const int*)d_in[10];
    const int* esrc = ei;
    const int* edst = ei + NEDGES;
    float* out = (float*)d_out;

    char* p = (char*)d_ws;
    auto alloc = [&](size_t bytes) -> char* {
        char* r = p;
        p += (bytes + 255) & ~(size_t)255;
        return r;
    };
    unsigned short* hhv = (unsigned short*)alloc((size_t)NROWS * 256 * 2);
    float* a        = (float*)alloc((size_t)NROWS * 4);
    int* cursor     = (int*)alloc((size_t)NNODES * 4);
    int* srcs_pad   = (int*)alloc((size_t)NNODES * MAXDEG * 4);
    unsigned short* WF = (unsigned short*)alloc((size_t)4 * 128 * 128 * 2);

    prep_kernel<<<111, 256, 0, stream>>>(Wp, Wq, Wk, Wv, WF, cursor);
    scatter_pad_kernel<<<(NEDGES + 255) / 256, 256, 0, stream>>>(esrc, edst, cursor, srcs_pad);
    hv_kernel<<<NROWS / QTM, 256, 0, stream>>>(x, WF, Bv, hhv);
    alpha_kernel<<<NROWS / QTM, 256, 0, stream>>>(hhv, WF, Bq, Bk, a);
    agg_kernel<<<NROWS / 4, 256, 0, stream>>>(hhv, a, cursor, srcs_pad, ln_g, ln_b, out);
}

// Round 11
// 159.581 us; speedup vs baseline: 1.0566x; 1.0293x over previous
//
#include <hip/hip_runtime.h>
#include <hip/hip_bf16.h>

#define NNODES 20000
#define NEDGES 320000
#define BATCH  2
#define D      128
#define EPSF   1e-5f
#define QTM    64     // rows per block (4 waves x 16 rows)
#define XS_LD  136
#define MAXDEG 64
#define NROWS  (BATCH * NNODES)

typedef __attribute__((ext_vector_type(8))) short bf16x8;
typedef __attribute__((ext_vector_type(4))) float f32x4;

static __device__ __forceinline__ unsigned short f2bf(float f) {
    __hip_bfloat16 h = __float2bfloat16(f);
    return *reinterpret_cast<unsigned short*>(&h);
}
static __device__ __forceinline__ float bfu(unsigned short u) {
    union { unsigned int i; float f; } cv;
    cv.i = ((unsigned int)u) << 16;
    return cv.f;
}

// ---------------- prep: frag-ordered bf16 weights (blocks 0..31) + cursor clear (32..110) ----
__global__ __launch_bounds__(256) void prep_kernel(
    const float* __restrict__ Wp, const float* __restrict__ Wq,
    const float* __restrict__ Wk, const float* __restrict__ Wv,
    unsigned short* __restrict__ WF,
    int* __restrict__ cursor)
{
    int bid = blockIdx.x;
    if (bid < 32) {
        int sg = bid * 256 + threadIdx.x;   // slot 0..8191
        int mat = sg >> 11, rem = sg & 2047;
        int f = rem >> 6, l = rem & 63;
        int nt = f >> 2, ks = f & 3;
        int c = l & 15, g = l >> 4;
        const float* W = (mat == 0) ? Wp : (mat == 1) ? Wq : (mat == 2) ? Wk : Wv;
        int n = nt * 16 + c;
        #pragma unroll
        for (int i = 0; i < 8; ++i) {
            int k = ks * 32 + g * 8 + i;
            WF[(size_t)sg * 8 + i] = f2bf(W[k * 128 + n]);
        }
    } else {
        int idx = (bid - 32) * 256 + threadIdx.x;
        if (idx < NNODES) cursor[idx] = 0;
    }
}

// ---------------- padded-CSR scatter (srcs only) ----------------
__global__ __launch_bounds__(256) void scatter_pad_kernel(
    const int* __restrict__ src, const int* __restrict__ dst,
    int* __restrict__ cursor,             // exits holding deg
    int* __restrict__ srcs_pad)           // [NNODES][MAXDEG]
{
    int e = blockIdx.x * 256 + threadIdx.x;
    if (e >= NEDGES) return;
    int d = dst[e], s = src[e];
    int slot = atomicAdd(&cursor[d], 1);
    if (slot < MAXDEG) srcs_pad[d * MAXDEG + slot] = s;
}

#define DECL_STAGE_MACROS                                               \
    bf16x8 wreg[8];
#define LOAD_W_REGS(MAT_OFF)                                            \
    _Pragma("unroll")                                                   \
    for (int q = 0; q < 8; ++q)                                         \
        wreg[q] = *(const bf16x8*)(WF + (MAT_OFF) + (q * 256 + t) * 8);
#define WRITE_W_LDS()                                                   \
    _Pragma("unroll")                                                   \
    for (int q = 0; q < 8; ++q)                                         \
        *(bf16x8*)&Wbuf[(q * 256 + t) * 8] = wreg[q];

// ---------------- h = x @ Wp -> h_out[NROWS][128] bf16 ----------------
// 4 waves x independent 16-row tiles; single barrier (weight stage).
__global__ __launch_bounds__(256) void h_kernel(
    const float* __restrict__ x,
    const unsigned short* __restrict__ WF,
    unsigned short* __restrict__ h_out)
{
    __shared__ unsigned short Wbuf[16384];
    __shared__ unsigned short Hs[4][16][XS_LD];
    const int t = threadIdx.x;
    const long row0 = (long)blockIdx.x * QTM;
    const int w = t >> 6, l = t & 63;
    const int g = l >> 4, c = l & 15;
    const int rw = w * 16;
    DECL_STAGE_MACROS

    LOAD_W_REGS(0)

    bf16x8 ax[4];
    {
        const float* xr = x + (row0 + rw + c) * D;
        #pragma unroll
        for (int ks = 0; ks < 4; ++ks) {
            float4 u0 = *(const float4*)(xr + ks * 32 + g * 8);
            float4 u1 = *(const float4*)(xr + ks * 32 + g * 8 + 4);
            bf16x8 f;
            f[0] = (short)f2bf(u0.x); f[1] = (short)f2bf(u0.y);
            f[2] = (short)f2bf(u0.z); f[3] = (short)f2bf(u0.w);
            f[4] = (short)f2bf(u1.x); f[5] = (short)f2bf(u1.y);
            f[6] = (short)f2bf(u1.z); f[7] = (short)f2bf(u1.w);
            ax[ks] = f;
        }
    }

    WRITE_W_LDS();
    __syncthreads();

    f32x4 hacc[8];
    #pragma unroll
    for (int nt = 0; nt < 8; ++nt) hacc[nt] = f32x4{0.f, 0.f, 0.f, 0.f};
    #pragma unroll
    for (int nt = 0; nt < 8; ++nt)
        #pragma unroll
        for (int ks = 0; ks < 4; ++ks) {
            bf16x8 b = *(const bf16x8*)&Wbuf[((nt * 4 + ks) * 64 + l) * 8];
            hacc[nt] = __builtin_amdgcn_mfma_f32_16x16x32_bf16(ax[ks], b, hacc[nt], 0, 0, 0);
        }
    #pragma unroll
    for (int nt = 0; nt < 8; ++nt)
        #pragma unroll
        for (int i = 0; i < 4; ++i)
            Hs[w][4 * g + i][nt * 16 + c] = f2bf(hacc[nt][i]);
    // wave-local coalesced store (same-wave LDS ordering via lgkmcnt)
    #pragma unroll
    for (int q = 0; q < 4; ++q) {
        int ch = q * 64 + l;                 // 256 chunks of 8 ushorts
        int r = ch >> 4, off = (ch & 15) << 3;
        *(bf16x8*)(h_out + (row0 + rw + r) * D + off) = *(const bf16x8*)&Hs[w][r][off];
    }
}

// ---------------- alpha = dot(h@Wq+bq, h@Wk+bk)*0.25 ----------------
__global__ __launch_bounds__(256) void alpha_kernel(
    const unsigned short* __restrict__ h,
    const unsigned short* __restrict__ WF,
    const float* __restrict__ Bq, const float* __restrict__ Bk,
    float* __restrict__ a_out)
{
    __shared__ unsigned short Wbuf[16384];
    const int t = threadIdx.x;
    const long row0 = (long)blockIdx.x * QTM;
    const int w = t >> 6, l = t & 63;
    const int g = l >> 4, c = l & 15;
    const int rw = w * 16;
    DECL_STAGE_MACROS

    LOAD_W_REGS(16384)                       // Wq

    bf16x8 ah[4];
    {
        const unsigned short* hr = h + (row0 + rw + c) * D;
        #pragma unroll
        for (int ks = 0; ks < 4; ++ks)
            ah[ks] = *(const bf16x8*)(hr + ks * 32 + g * 8);
    }

    WRITE_W_LDS();
    __syncthreads();
    LOAD_W_REGS(32768)                       // prefetch Wk during mQ

    f32x4 qacc[8];
    #pragma unroll
    for (int nt = 0; nt < 8; ++nt) qacc[nt] = f32x4{0.f, 0.f, 0.f, 0.f};
    #pragma unroll
    for (int nt = 0; nt < 8; ++nt)
        #pragma unroll
        for (int ks = 0; ks < 4; ++ks) {
            bf16x8 b = *(const bf16x8*)&Wbuf[((nt * 4 + ks) * 64 + l) * 8];
            qacc[nt] = __builtin_amdgcn_mfma_f32_16x16x32_bf16(ah[ks], b, qacc[nt], 0, 0, 0);
        }
    __syncthreads();
    WRITE_W_LDS();                           // Wk
    __syncthreads();

    float p[4] = {0.f, 0.f, 0.f, 0.f};
    #pragma unroll
    for (int nt = 0; nt < 8; ++nt) {
        f32x4 kacc = f32x4{0.f, 0.f, 0.f, 0.f};
        #pragma unroll
        for (int ks = 0; ks < 4; ++ks) {
            bf16x8 b = *(const bf16x8*)&Wbuf[((nt * 4 + ks) * 64 + l) * 8];
            kacc = __builtin_amdgcn_mfma_f32_16x16x32_bf16(ah[ks], b, kacc, 0, 0, 0);
        }
        float bq = Bq[nt * 16 + c];
        float bk = Bk[nt * 16 + c];
        #pragma unroll
        for (int i = 0; i < 4; ++i)
            p[i] += (qacc[nt][i] + bq) * (kacc[i] + bk);
    }
    #pragma unroll
    for (int off = 1; off < 16; off <<= 1)
        #pragma unroll
        for (int i = 0; i < 4; ++i) p[i] += __shfl_xor(p[i], off, 64);
    if (c == 0)
        #pragma unroll
        for (int i = 0; i < 4; ++i)
            a_out[row0 + rw + 4 * g + i] = p[i] * 0.25f;
}

// ---------------- aggregation: gather h ONLY (256B/edge); write Hw | S ----------------
// one WAVE per node; lane: eh = edge slot (0..3), cq = 16-B chunk (8 channels).
// Hw = sum w_e h[src]; S = (sum h[src])/deg + bv (bv masked when deg==0).
__global__ __launch_bounds__(256) void agg_kernel(
    const unsigned short* __restrict__ h,     // [NROWS][128]
    const float* __restrict__ a,
    const int* __restrict__ deg_arr,
    const int* __restrict__ srcs_pad,
    const float* __restrict__ Bv,
    unsigned short* __restrict__ HwS)         // [NROWS][256]: [0:128]=Hw, [128:256]=S
{
    const int t = threadIdx.x;
    const int w = t >> 6, l = t & 63;
    const int flat = blockIdx.x * 4 + w;
    const int n = flat % NNODES;
    const int b = flat / NNODES;
    const int bN = b * NNODES;
    const int deg = min(deg_arr[n], MAXDEG);
    const bool valid = l < deg;

    int   sr_l = valid ? srcs_pad[n * MAXDEG + l] : 0;
    float av_l = valid ? a[bN + sr_l] : -1e30f;

    float m = av_l;
    #pragma unroll
    for (int off = 32; off >= 1; off >>= 1) m = fmaxf(m, __shfl_xor(m, off, 64));
    float e_l = valid ? __expf(av_l - m) : 0.f;
    float s = e_l;
    #pragma unroll
    for (int off = 32; off >= 1; off >>= 1) s += __shfl_xor(s, off, 64);
    const float inv_s = (deg > 0) ? 1.f / s : 0.f;
    const float inv_d = 1.f / (float)max(deg, 1);
    const float w_l = e_l * inv_s;

    const int eh = l >> 4;          // edge slot in quad
    const int cq = l & 15;          // 16-B chunk = channels 8*cq..+7
    float aw[8] = {0,0,0,0,0,0,0,0};
    float au[8] = {0,0,0,0,0,0,0,0};
    const long base = ((long)bN << 7) + (cq << 3);

    #define PREP(JJ, OF, WW, UU)  {                                     \
        int sel = ((JJ) << 2) + eh;                                     \
        bool ev = sel < deg;                                            \
        int sc = ev ? sel : 0;                                          \
        int srj = __shfl(sr_l, sc, 64);                                 \
        float wj = __shfl(w_l, sc, 64);                                 \
        WW = ev ? wj : 0.f;                                             \
        UU = ev ? 1.f : 0.f;                                            \
        OF = base + ((long)srj << 7);  }

    const int iters = (deg + 3) >> 2;
    for (int j0 = 0; j0 < iters; j0 += 2) {
        long oa, ob; float wa, ua, wb, ub;
        PREP(j0,     oa, wa, ua)
        PREP(j0 + 1, ob, wb, ub)
        bf16x8 da = *(const bf16x8*)(h + oa);   // 2 gathers in flight (8 rows across wave)
        bf16x8 db = *(const bf16x8*)(h + ob);
        #pragma unroll
        for (int i = 0; i < 8; ++i) {
            float fv = bfu((unsigned short)da[i]);
            aw[i] += wa * fv;
            au[i] += ua * fv;
        }
        #pragma unroll
        for (int i = 0; i < 8; ++i) {
            float fv = bfu((unsigned short)db[i]);
            aw[i] += wb * fv;
            au[i] += ub * fv;
        }
    }
    #undef PREP

    // fold the 4 eh groups (lanes l, l^16, l^32, l^48 share cq)
    #pragma unroll
    for (int i = 0; i < 8; ++i) {
        aw[i] += __shfl_xor(aw[i], 16, 64);
        au[i] += __shfl_xor(au[i], 16, 64);
        aw[i] += __shfl_xor(aw[i], 32, 64);
        au[i] += __shfl_xor(au[i], 32, 64);
    }
    if (l < 16) {
        const float bvm = (deg > 0) ? 1.f : 0.f;
        bf16x8 w8, s8;
        #pragma unroll
        for (int i = 0; i < 8; ++i) {
            w8[i] = (short)f2bf(aw[i]);
            s8[i] = (short)f2bf(au[i] * inv_d + bvm * Bv[(cq << 3) + i]);
        }
        unsigned short* op = HwS + (long)flat * 256 + (cq << 3);
        *(bf16x8*)op = w8;
        *(bf16x8*)(op + 128) = s8;
    }
}

// ---------------- final: out = LN( Hw @ Wv + S ) ----------------
__global__ __launch_bounds__(256) void final_kernel(
    const unsigned short* __restrict__ HwS,
    const unsigned short* __restrict__ WF,
    const float* __restrict__ ln_g, const float* __restrict__ ln_b,
    float* __restrict__ out)
{
    __shared__ unsigned short Wbuf[16384];
    const int t = threadIdx.x;
    const long row0 = (long)blockIdx.x * QTM;
    const int w = t >> 6, l = t & 63;
    const int g = l >> 4, c = l & 15;
    const int rw = w * 16;
    DECL_STAGE_MACROS

    LOAD_W_REGS(49152)                       // Wv

    bf16x8 ah[4];
    {
        const unsigned short* hr = HwS + (row0 + rw + c) * 256;  // Hw half
        #pragma unroll
        for (int ks = 0; ks < 4; ++ks)
            ah[ks] = *(const bf16x8*)(hr + ks * 32 + g * 8);
    }

    WRITE_W_LDS();
    __syncthreads();

    float val[8][4];
    #pragma unroll
    for (int nt = 0; nt < 8; ++nt) {
        f32x4 vacc = f32x4{0.f, 0.f, 0.f, 0.f};
        #pragma unroll
        for (int ks = 0; ks < 4; ++ks) {
            bf16x8 b = *(const bf16x8*)&Wbuf[((nt * 4 + ks) * 64 + l) * 8];
            vacc = __builtin_amdgcn_mfma_f32_16x16x32_bf16(ah[ks], b, vacc, 0, 0, 0);
        }
        #pragma unroll
        for (int i = 0; i < 4; ++i) {
            long R = row0 + rw + 4 * g + i;
            val[nt][i] = vacc[i] + bfu(HwS[R * 256 + 128 + nt * 16 + c]);
        }
    }
    // LayerNorm per row (rows 4g+i; cols spread over nt x c-lanes)
    float sum[4] = {0,0,0,0}, sq[4] = {0,0,0,0};
    #pragma unroll
    for (int nt = 0; nt < 8; ++nt)
        #pragma unroll
        for (int i = 0; i < 4; ++i) {
            sum[i] += val[nt][i];
            sq[i]  += val[nt][i] * val[nt][i];
        }
    #pragma unroll
    for (int off = 8; off >= 1; off >>= 1)
        #pragma unroll
        for (int i = 0; i < 4; ++i) {
            sum[i] += __shfl_xor(sum[i], off, 64);
            sq[i]  += __shfl_xor(sq[i],  off, 64);
        }
    float mu[4], rstd[4];
    #pragma unroll
    for (int i = 0; i < 4; ++i) {
        mu[i] = sum[i] * (1.f / 128.f);
        float var = sq[i] * (1.f / 128.f) - mu[i] * mu[i];
        rstd[i] = rsqrtf(var + EPSF);
    }
    #pragma unroll
    for (int nt = 0; nt < 8; ++nt) {
        float gg = ln_g[nt * 16 + c];
        float bb = ln_b[nt * 16 + c];
        #pragma unroll
        for (int i = 0; i < 4; ++i) {
            long R = row0 + rw + 4 * g + i;
            out[R * D + nt * 16 + c] = (val[nt][i] - mu[i]) * rstd[i] * gg + bb;
        }
    }
}

// ---------------- launch ----------------

extern "C" void kernel_launch(void* const* d_in, const int* in_sizes, int n_in,
                              void* d_out, int out_size, void* d_ws, size_t ws_size,
                              hipStream_t stream)
{
    const float* x    = (const float*)d_in[0];
    const float* Wp   = (const float*)d_in[1];
    const float* Wq   = (const float*)d_in[2];
    const float* Bq   = (const float*)d_in[3];
    const float* Wk   = (const float*)d_in[4];
    const float* Bk   = (const float*)d_in[5];
    const float* Wv   = (const float*)d_in[6];
    const float* Bv   = (const float*)d_in[7];
    const float* ln_g = (const float*)d_in[8];
    const float* ln_b = (const float*)d_in[9];
    const int*   ei   = (const int*)d_in[10];
    const int* esrc = ei;
    const int* edst = ei + NEDGES;
    float* out = (float*)d_out;

    char* p = (char*)d_ws;
    auto alloc = [&](size_t bytes) -> char* {
        char* r = p;
        p += (bytes + 255) & ~(size_t)255;
        return r;
    };
    unsigned short* h   = (unsigned short*)alloc((size_t)NROWS * D * 2);
    unsigned short* HwS = (unsigned short*)alloc((size_t)NROWS * 256 * 2);
    float* a        = (float*)alloc((size_t)NROWS * 4);
    int* cursor     = (int*)alloc((size_t)NNODES * 4);
    int* srcs_pad   = (int*)alloc((size_t)NNODES * MAXDEG * 4);
    unsigned short* WF = (unsigned short*)alloc((size_t)4 * 128 * 128 * 2);

    prep_kernel<<<111, 256, 0, stream>>>(Wp, Wq, Wk, Wv, WF, cursor);
    scatter_pad_kernel<<<(NEDGES + 255) / 256, 256, 0, stream>>>(esrc, edst, cursor, srcs_pad);
    h_kernel<<<NROWS / QTM, 256, 0, stream>>>(x, WF, h);
    alpha_kernel<<<NROWS / QTM, 256, 0, stream>>>(h, WF, Bq, Bk, a);
    agg_kernel<<<NROWS / 4, 256, 0, stream>>>(h, a, cursor, srcs_pad, Bv, HwS);
    final_kernel<<<NROWS / QTM, 256, 0, stream>>>(HwS, WF, ln_g, ln_b, out);
}